// Round 9
// baseline (309.096 us; speedup 1.0000x reference)
//
#include <hip/hip_runtime.h>
#include <math.h>

// Problem constants
#define D_FEAT 8192
#define NC4    2048          // float4 columns per R row
#define T_RES  2048
#define LORD   16

// Geometry: 256 blocks x 512 threads. Block owns a 32-column slab of R
// (all 2048 rows) in registers: thread (cg=tid&7, rg=tid>>3) holds rows
// rg+64*i (i<32) of float4-column (bid*8+cg). 32 float4 = 128 regs.
// R9 = R8 skeleton + intra-block micro-opts: float4 owner reduce (one less
// barrier, coalesced), owner-side dots on wave 0, owner-pre-reduced b2
// (consumers read 1 word, not 1KB), float4 flush/staging.
#define NTHR 512
#define NBLK 256
#define RPT  32
#define NOWN 64              // u-reduction chunk owners (32 rows each)
#define CH   32              // rows per chunk
#define NREPA 8              // A-flag replicas (pollers = 64 owners -> 8/rep)
#define NREPB 16             // B-flag replicas (pollers = 256 blocks -> 16/rep)

// ---- Global workspace layout (float offsets) ----
// Zeroed region: flags (~212 KB memset per launch).
#define G_FUPA  0                              // 17 x NREPA x 256 partial-ready
#define G_FREDB (G_FUPA + 17*NREPA*256)        // 17 x NREPB x NOWN owner words
#define G_FNUM  (G_FREDB + 17*NREPB*NOWN)      // NREPA x 256 (block 0 polls)
#define G_ZEND  (G_FNUM + NREPA*256)
// Rotated single-write-then-single-read regions (cached reads safe: caches
// invalidated at dispatch; each slot written once then read once per launch):
#define G_URAW  G_ZEND                         // 17 x 2048 reduced u (slot16 = R f)
#define G_UUP   (G_URAW + 17*2048)             // 64 |u_init|^2 owner partials
#define G_FFP   (G_UUP + 64)                   // 256 f.f partials
#define G_B2P   (G_FFP + 256)                  // 16 x 256 b2 partials (slot j)
#define G_B2R   (G_B2P + 16*256)               // 16 x 64 owner-reduced b2
#define G_DP    (G_B2R + 16*64)                // 16 x 16 x 64 dot owner partials
#define G_NUMP  (G_DP + 16*16*64)              // 16 x 256
#define G_DENP  (G_NUMP + 16*256)              // 16 x 256
#define G_UPB   ((G_DENP + 16*256 + 1023) & ~1023)  // 17 x UPSLOT u partials
#define UPSLOT  (NOWN*NBLK*CH)                 // 524288 floats = 2MB

// ---- MALL-coherent uncached ops (writes + sync polling)
__device__ __forceinline__ void astore(float* p, float v) {
    __hip_atomic_store(p, v, __ATOMIC_RELAXED, __HIP_MEMORY_SCOPE_AGENT);
}
__device__ __forceinline__ void astore64(unsigned long long* p,
                                         unsigned long long v) {
    __hip_atomic_store(p, v, __ATOMIC_RELAXED, __HIP_MEMORY_SCOPE_AGENT);
}
__device__ __forceinline__ void astoreu(unsigned* p, unsigned v) {
    __hip_atomic_store(p, v, __ATOMIC_RELAXED, __HIP_MEMORY_SCOPE_AGENT);
}
__device__ __forceinline__ unsigned aloadu(const unsigned* p) {
    return __hip_atomic_load(p, __ATOMIC_RELAXED, __HIP_MEMORY_SCOPE_AGENT);
}

// Sync A (all 256 produce partials; 64 owners consume): __syncthreads drains
// vmcnt so payload astores are at MALL before the flag stores issue. Distinct
// words per producer -> no RMW serialization.
__device__ __forceinline__ void sigA(unsigned* fl, int bid) {
    __syncthreads();
    if (threadIdx.x < NREPA) astoreu(&fl[threadIdx.x*256 + bid], 1u);
}
// Owners poll replica (bid&7): 8 owner-blocks x 64 lanes per replica — low
// fan-in (R1 lesson: high poller fan-in saturates the fabric).
__device__ __forceinline__ void pollA(const unsigned* fl, int bid) {
    if (threadIdx.x < 64) {
        const unsigned* p = fl + (bid & (NREPA-1))*256 + 4*threadIdx.x;
        for (;;) {
            unsigned a = aloadu(p) & aloadu(p+1) & aloadu(p+2) & aloadu(p+3);
            if (__all((int)a)) break;
            __builtin_amdgcn_s_sleep(2);
        }
    }
    __syncthreads();
}

// Sync B (64 owners produce reduced u; all 256 consume): owner bid writes ITS
// WORD in each of NREPB replicas (plain stores, distinct addresses). Consumer:
// 64 lanes poll the 64 owner words of replica (bid&15) -> 16 blocks/replica.
__device__ __forceinline__ void sigB(unsigned* fl, int bid) {
    __syncthreads();   // drain reduced-u / DP / B2R / UUP stores
    if (threadIdx.x < NREPB) astoreu(&fl[threadIdx.x*NOWN + bid], 1u);
}
__device__ __forceinline__ void pollB(const unsigned* fl, int bid) {
    if (threadIdx.x < 64) {
        const unsigned* p = fl + (bid & (NREPB-1))*NOWN + threadIdx.x;
        while (!__all(aloadu(p) != 0u))
            __builtin_amdgcn_s_sleep(2);
    }
    __syncthreads();
}

__device__ __forceinline__ float wave_sum64(float s) {
    #pragma unroll
    for (int m = 1; m < 64; m <<= 1) s += __shfl_xor(s, m, 64);
    return s;
}
// Reduce over lanes 0..31 (lane 0 result valid; halves stay independent).
__device__ __forceinline__ float sum32(float s) {
    #pragma unroll
    for (int m = 1; m < 32; m <<= 1) s += __shfl_xor(s, m, 64);
    return s;
}

// slab u contribution into LDS: row t=rg+64i, d = R[t][slab] . w_slab
__device__ __forceinline__ void u_pass_lds(const float4 (&rr)[RPT],
                                           const float* wsl, float* ubuf,
                                           int rg, int cg) {
    const float4 w4 = ((const float4*)wsl)[cg];
    #pragma unroll
    for (int i = 0; i < RPT; ++i) {
        float d = rr[i].x*w4.x + rr[i].y*w4.y + rr[i].z*w4.z + rr[i].w*w4.w;
        d += __shfl_xor(d, 1, 64);
        d += __shfl_xor(d, 2, 64);
        d += __shfl_xor(d, 4, 64);
        if (cg == 0) ubuf[rg + 64*i] = d;
    }
}

// Flush 2048 partials, 32-row-chunk layout UP[t>>5][bid][t&31]: thread takes
// 4 consecutive t (one ubuf float4), two 8B uncached stores; 8 lanes cover a
// 128B contiguous run -> full-line write packets (R2/R7 lesson: half-line
// packets cost ~25-28us).
__device__ __forceinline__ void flush_up(float* UP, const float* ubuf,
                                         int bid, int tid) {
    const int t0 = tid << 2;
    const float4 v = ((const float4*)ubuf)[tid];
    float* dst = &UP[(size_t)(t0 >> 5)*(NBLK*CH) + bid*CH + (t0 & 31)];
    unsigned long long lo, hi;
    __builtin_memcpy(&lo, &v.x, 8);
    __builtin_memcpy(&hi, &v.z, 8);
    astore64((unsigned long long*)(dst), lo);
    astore64((unsigned long long*)(dst + 2), hi);
}

// Owner (bid<64) reduces its 32-row chunk from 8KB of partials:
// 4 coalesced float4 loads/thread (fixed order m ascending: blocks
// tid>>3 + 64m), xor-shuffle {8,16,32} combines lanes sharing lane&7
// (blocks 8w..8w+7), LDS stage over waves. Lane l<8 of wave w holds rows
// 4l..4l+3. Returns this thread's reduced u (valid for tid<32), which is
// also stored to udst (uncached) and uhrow (LDS history).
__device__ __forceinline__ float owner_reduce(const float* __restrict__ UP,
                                              float* udst, float (*red)[8][4],
                                              float* uhrow, int bid,
                                              int tid, int lane, int wave) {
    const float4* b4 = (const float4*)(UP + (size_t)bid*(NBLK*CH));
    float4 s = b4[tid];
    #pragma unroll
    for (int m = 1; m < 4; ++m) {
        const float4 v = b4[tid + 512*m];
        s.x += v.x; s.y += v.y; s.z += v.z; s.w += v.w;
    }
    #pragma unroll
    for (int m = 8; m < 64; m <<= 1) {
        s.x += __shfl_xor(s.x, m, 64); s.y += __shfl_xor(s.y, m, 64);
        s.z += __shfl_xor(s.z, m, 64); s.w += __shfl_xor(s.w, m, 64);
    }
    if (lane < 8) {
        red[wave][lane][0] = s.x; red[wave][lane][1] = s.y;
        red[wave][lane][2] = s.z; red[wave][lane][3] = s.w;
    }
    __syncthreads();
    float u = 0.f;
    if (tid < 32) {
        #pragma unroll
        for (int w = 0; w < 8; ++w) u += red[w][tid >> 2][tid & 3];
        astore(&udst[bid*CH + tid], u);   // 32 lanes -> 128B contiguous
        uhrow[tid] = u;
    }
    return u;
}

// y slab partial: acc = -sum_t u[t]*R[t, my col4] over this thread's 32 rows
__device__ __forceinline__ float4 y_pass(const float4 (&rr)[RPT],
                                         const float* u, int rg) {
    float4 acc = make_float4(0.f, 0.f, 0.f, 0.f);
    #pragma unroll
    for (int i = 0; i < RPT; ++i) {
        const float ut = u[rg + 64*i];
        acc.x -= ut*rr[i].x; acc.y -= ut*rr[i].y;
        acc.z -= ut*rr[i].z; acc.w -= ut*rr[i].w;
    }
    return acc;
}

// Reduce per-thread y partials (over rg) into ysl[32]. Fixed order everywhere.
__device__ __forceinline__ void y_reduce(float4 acc, float (*red)[8][4],
                                         float* ysl, int wave, int lane, int tid) {
    #pragma unroll
    for (int m = 8; m < 64; m <<= 1) {
        acc.x += __shfl_xor(acc.x, m, 64); acc.y += __shfl_xor(acc.y, m, 64);
        acc.z += __shfl_xor(acc.z, m, 64); acc.w += __shfl_xor(acc.w, m, 64);
    }
    if (lane < 8) {
        red[wave][lane][0] = acc.x; red[wave][lane][1] = acc.y;
        red[wave][lane][2] = acc.z; red[wave][lane][3] = acc.w;
    }
    __syncthreads();
    if (tid < 32) {
        const int g = tid >> 2, comp = tid & 3;
        float s = 0.f;
        #pragma unroll
        for (int w = 0; w < 8; ++w) s += red[w][g][comp];
        ysl[g*4 + comp] = s;
    }
    __syncthreads();
}

__global__ __launch_bounds__(NTHR, 2) void k_all(
    const float* __restrict__ Rm, const float* __restrict__ f,
    const float* __restrict__ Dm, float* __restrict__ out,
    float* __restrict__ ws)
{
    __shared__ __align__(16) float ubuf[2048];
    __shared__ float red[8][8][4];
    __shared__ float uh[17][32];       // owner-only: chunk history for dots
    __shared__ __align__(16) float ysl[32];
    __shared__ __align__(16) float dirs[32];
    __shared__ __align__(16) float fsl[32];
    __shared__ float Wh[LORD][32];
    __shared__ float bh[LORD];
    __shared__ float alph[LORD];
    __shared__ float dotl[LORD];
    __shared__ float cf[LORD];
    __shared__ float misc[4];   // [0]=b2j  [2]=ff  [3]=uu

    unsigned* fupA  = (unsigned*)(ws + G_FUPA);
    unsigned* fredB = (unsigned*)(ws + G_FREDB);
    unsigned* fnum  = (unsigned*)(ws + G_FNUM);
    float* uraw = ws + G_URAW;
    float* UUP  = ws + G_UUP;
    float* FFP  = ws + G_FFP;
    float* B2P  = ws + G_B2P;
    float* B2R  = ws + G_B2R;
    float* DP   = ws + G_DP;
    float* NUMP = ws + G_NUMP;
    float* DENP = ws + G_DENP;
    float* UPB  = ws + G_UPB;

    const int tid = threadIdx.x, bid = blockIdx.x;
    const int cg = tid & 7, rg = tid >> 3;
    const int lane = tid & 63, wave = tid >> 6;
    const bool owner = bid < NOWN;

    // Load R column-slab into registers ONCE.
    const float4* R4 = (const float4*)Rm;
    float4 rr[RPT];
    #pragma unroll
    for (int i = 0; i < RPT; ++i)
        rr[i] = R4[(size_t)(rg + 64*i)*NC4 + (bid << 3) + cg];

    // ===== I1: f slab -> LDS ; FFP partial ; u_init partials (UP slot 16) =====
    if (wave == 0) {
        float4 fv = make_float4(0.f, 0.f, 0.f, 0.f);
        if (lane < 8) { fv = ((const float4*)f)[(bid << 3) + lane];
                        ((float4*)fsl)[lane] = fv; }
        float s2 = fv.x*fv.x + fv.y*fv.y + fv.z*fv.z + fv.w*fv.w;
        s2 += __shfl_xor(s2, 1, 64);
        s2 += __shfl_xor(s2, 2, 64);
        s2 += __shfl_xor(s2, 4, 64);
        if (lane == 0) astore(&FFP[bid], s2);
    }
    __syncthreads();
    u_pass_lds(rr, fsl, ubuf, rg, cg);
    __syncthreads();
    flush_up(UPB + (size_t)16*UPSLOT, ubuf, bid, tid);
    sigA(fupA + 16*NREPA*256, bid);

    // ===== I2 (owners): reduce UP16 -> uraw[16]=Rf ; uu partial =====
    if (owner) {
        pollA(fupA + 16*NREPA*256, bid);
        const float ureg = owner_reduce(UPB + (size_t)16*UPSLOT,
                                        uraw + 16*2048, red, uh[16],
                                        bid, tid, lane, wave);
        if (wave == 0) {
            float p = (lane < 32) ? ureg*ureg : 0.f;
            p = sum32(p);
            if (lane == 0) astore(&UUP[bid], p);
        }
        sigB(fredB + 16*NREPB*NOWN, bid);
    }
    pollB(fredB + 16*NREPB*NOWN, bid);

    // ===== I3: uu+ff reduce (all, fixed order) ; y=Hf ; W0 ; u(W0) slot 0 =====
    ((float4*)ubuf)[tid] = ((const float4*)(uraw + 16*2048))[tid];
    if (wave == 0) {
        float s = UUP[lane];          // 64 owner partials
        s = wave_sum64(s);
        if (lane == 0) misc[3] = s;
    }
    if (wave == 1) {
        float s = 0.f;
        #pragma unroll
        for (int i = 0; i < 4; ++i) s += FFP[lane + 64*i];
        s = wave_sum64(s);
        if (lane == 0) misc[2] = s;
    }
    __syncthreads();
    {
        float4 acc = y_pass(rr, ubuf, rg);
        y_reduce(acc, red, ysl, wave, lane, tid);
        const float E = -misc[3] / (misc[2] + 1e-15f);
        float v = 0.f;
        if (tid < 32) { v = E*fsl[tid] - ysl[tid]; Wh[0][tid] = v; }
        if (wave == 0) {
            float s = (lane < 32) ? v*v : 0.f;
            s = wave_sum64(s);
            if (lane == 0) astore(&B2P[0*256 + bid], s);
        }
        __syncthreads();
        u_pass_lds(rr, Wh[0], ubuf, rg, cg);
        __syncthreads();
        flush_up(UPB + (size_t)0*UPSLOT, ubuf, bid, tid);
    }
    sigA(fupA + 0*NREPA*256, bid);

    // ===== Lanczos steps j=0..15 =====
    for (int j = 0; j < LORD; ++j) {
        float* UPj = UPB + (size_t)j*UPSLOT;
        float* DPj = DP + j*(16*NOWN);
        // --- Phase 1 (owners): reduce u ; wave0 dots vs history ; wave1 b2 ---
        if (owner) {
            pollA(fupA + j*NREPA*256, bid);
            const float ureg = owner_reduce(UPj, uraw + (size_t)j*2048, red,
                                            uh[j], bid, tid, lane, wave);
            if (wave == 0) {
                #pragma unroll 1
                for (int k = 0; k <= j; ++k) {
                    float p = (lane < 32) ? ureg * uh[k][lane] : 0.f;
                    p = sum32(p);
                    if (lane == 0) astore(&DPj[k*NOWN + bid], p);
                }
            }
            if (wave == 1) {   // b2 pre-reduce: B2P visible after pollA
                float s = 0.f;
                #pragma unroll
                for (int i = 0; i < 4; ++i) s += B2P[j*256 + lane + 64*i];
                s = wave_sum64(s);
                if (lane == 0) astore(&B2R[j*64 + bid], s);
            }
            sigB(fredB + j*NREPB*NOWN, bid);
        }
        pollB(fredB + j*NREPB*NOWN, bid);

        // --- Phase 2 (all): RAW u -> ubuf (float4, early); dots reduce;
        // b2 from owner pre-reduce (1 word); one barrier covers all. ---
        if (j < LORD - 1)
            ((float4*)ubuf)[tid] = ((const float4*)(uraw + (size_t)j*2048))[tid];
        for (int k = wave; k <= j; k += 8) {
            float s = DPj[k*NOWN + lane];     // 64 owner partials
            s = wave_sum64(s);
            if (lane == 0) dotl[k] = s;
        }
        if (tid == 256) misc[0] = B2R[j*64 + (bid & 63)];
        __syncthreads();
        const float b2j = misc[0];
        const float bj  = sqrtf(fmaxf(b2j, 1e-60f));   // ref: w/max(b,1e-30)
        if (tid == 0) {
            bh[j]   = bj;
            alph[j] = -dotl[j] / fmaxf(b2j, 1e-60f);
        }
        if (j < LORD - 1) {
            float4 acc = y_pass(rr, ubuf, rg);   // RAW u
            y_reduce(acc, red, ysl, wave, lane, tid);
            const float inv = 1.0f / bj;
            // W_{j+1} = y/bj + sum_{k<=j} dot_jk/(b_j b_k^2) W_k (full reorth)
            float v = 0.f;
            if (tid < 32) {
                v = ysl[tid] * inv;
                for (int k = 0; k <= j; ++k)
                    v += (dotl[k] / (bj * bh[k] * bh[k])) * Wh[k][tid];
                Wh[j+1][tid] = v;
            }
            if (wave == 0) {
                float s = (lane < 32) ? v*v : 0.f;
                s = wave_sum64(s);
                if (lane == 0) astore(&B2P[(j+1)*256 + bid], s);
            }
            __syncthreads();
            u_pass_lds(rr, Wh[j+1], ubuf, rg, cg);
            __syncthreads();
            flush_up(UPB + (size_t)(j+1)*UPSLOT, ubuf, bid, tid);
            sigA(fupA + (j+1)*NREPA*256, bid);
        } else {
            __syncthreads();   // alph[15]/bh[15] visible
            // coeffs = normF * exp(-tau*T) e0 via fp64 Taylor — computed
            // REDUNDANTLY by every block (alph/bh are block-local and
            // bit-identical): no MALL hop.
            if (wave == 0) {
                double a = 0.0, bl = 0.0;
                if (lane < LORD)     a  = (double)alph[lane];
                if (lane < LORD - 1) bl = (double)bh[lane + 1];
                double bprev = __shfl_up(bl, 1, 64);
                if (lane == 0) bprev = 0.0;
                if (lane >= LORD) { a = 0.0; bl = 0.0; bprev = 0.0; }
                double v = (lane == 0) ? 1.0 : 0.0;
                double accd = v;
                for (int n = 1; n <= 30; ++n) {
                    double vm = __shfl_up(v, 1, 64);
                    if (lane == 0) vm = 0.0;
                    double vp = __shfl_down(v, 1, 64);
                    if (lane >= LORD - 1) vp = 0.0;
                    const double tv = a*v + bprev*vm + bl*vp;
                    v = tv * (-0.08 / (double)n);
                    accd += v;
                }
                if (lane < LORD)
                    cf[lane] = (float)accd * bh[0];
            }
            __syncthreads();   // cf visible to all waves
        }
    }

    // ===== F1: dir slab from LDS W history ; num/den partials =====
    if (tid < 32) {
        float s = 0.f;
        #pragma unroll
        for (int l = 0; l < LORD; ++l) s += cf[l] * Wh[l][tid] / bh[l];
        dirs[tid] = s;
    }
    __syncthreads();
    if (wave == 0 && lane < 16) {
        const float4* Dp = (const float4*)Dm + (size_t)lane*NC4 + (bid << 3);
        float num = 0.f, den = 0.f;
        #pragma unroll
        for (int g = 0; g < 8; ++g) {
            const float4 dv = Dp[g];
            const float4 dr = ((const float4*)dirs)[g];
            num += dv.x*dr.x + dv.y*dr.y + dv.z*dr.z + dv.w*dr.w;
            den += dv.x*dv.x + dv.y*dv.y + dv.z*dv.z + dv.w*dv.w;
        }
        astore(&NUMP[lane*256 + bid], num);
        astore(&DENP[lane*256 + bid], den);
    }
    sigA(fnum, bid);
    // Blocks != 0 are done; only block 0 waits for all num/den partials.

    // ===== F2: block 0 reduces num/den deterministically, writes out =====
    if (bid == 0) {
        pollA(fnum, 0);
        for (int p = wave; p < 16; p += 8) {
            float n = 0.f, d = 0.f;
            #pragma unroll
            for (int i = 0; i < 4; ++i) {
                n += NUMP[p*256 + lane + 64*i];
                d += DENP[p*256 + lane + 64*i];
            }
            n = wave_sum64(n);
            d = wave_sum64(d);
            if (lane == 0) out[p] = n / (d + 1e-4f);
        }
    }
}

extern "C" void kernel_launch(void* const* d_in, const int* in_sizes, int n_in,
                              void* d_out, int out_size, void* d_ws, size_t ws_size,
                              hipStream_t stream)
{
    (void)in_sizes; (void)n_in; (void)out_size; (void)ws_size;
    const float* f  = (const float*)d_in[0];
    const float* Rm = (const float*)d_in[1];
    const float* Dm = (const float*)d_in[2];
    float* outp = (float*)d_out;
    float* ws   = (float*)d_ws;
    // Zero flags (~212 KB). All rotated payload buffers are written before
    // their single read each launch.
    hipMemsetAsync(ws, 0, G_ZEND * sizeof(float), stream);
    // REGULAR launch (R7-validated: cut harness-visible overhead ~50us):
    // grid 256 blocks <= resident capacity, co-residency structurally
    // guaranteed; all inter-block sync is hand-rolled flag-based.
    hipLaunchKernelGGL(k_all, dim3(NBLK), dim3(NTHR), 0, stream,
                       Rm, f, Dm, outp, ws);
}

// Round 10
// 302.719 us; speedup vs baseline: 1.0211x; 1.0211x over previous
//
#include <hip/hip_runtime.h>
#include <math.h>

// Problem constants
#define D_FEAT 8192
#define NC4    2048          // float4 columns per R row
#define T_RES  2048
#define LORD   16

// Geometry: 256 blocks x 512 threads. Block owns a 32-column slab of R
// (all 2048 rows) in registers: thread (cg=tid&7, rg=tid>>3) holds rows
// rg+64*i (i<32) of float4-column (bid*8+cg). 32 float4 = 128 regs.
// R10 = R9 with the flush REVERTED to scalar interleaved stores. R9's
// float4/astore64 flush halved per-instruction density (8B/lane at 16B
// stride -> half-line packets, no cross-instruction write-combining on
// uncached agent stores): WRITE_SIZE 37->72MB, +27us. Packet rule (confirmed
// 4x: R2,R3,R7,R9): per-INSTRUCTION lane-contiguous full 64B lines.
#define NTHR 512
#define NBLK 256
#define RPT  32
#define NOWN 64              // u-reduction chunk owners (32 rows each)
#define CH   32              // rows per chunk
#define NREPA 8              // A-flag replicas (pollers = 64 owners -> 8/rep)
#define NREPB 16             // B-flag replicas (pollers = 256 blocks -> 16/rep)

// ---- Global workspace layout (float offsets) ----
// Zeroed region: flags (~212 KB memset per launch).
#define G_FUPA  0                              // 17 x NREPA x 256 partial-ready
#define G_FREDB (G_FUPA + 17*NREPA*256)        // 17 x NREPB x NOWN owner words
#define G_FNUM  (G_FREDB + 17*NREPB*NOWN)      // NREPA x 256 (block 0 polls)
#define G_ZEND  (G_FNUM + NREPA*256)
// Rotated single-write-then-single-read regions (cached reads safe: caches
// invalidated at dispatch; each slot written once then read once per launch):
#define G_URAW  G_ZEND                         // 17 x 2048 reduced u (slot16 = R f)
#define G_UUP   (G_URAW + 17*2048)             // 64 |u_init|^2 owner partials
#define G_FFP   (G_UUP + 64)                   // 256 f.f partials
#define G_B2P   (G_FFP + 256)                  // 16 x 256 b2 partials (slot j)
#define G_B2R   (G_B2P + 16*256)               // 16 x 64 owner-reduced b2
#define G_DP    (G_B2R + 16*64)                // 16 x 16 x 64 dot owner partials
#define G_NUMP  (G_DP + 16*16*64)              // 16 x 256
#define G_DENP  (G_NUMP + 16*256)              // 16 x 256
#define G_UPB   ((G_DENP + 16*256 + 1023) & ~1023)  // 17 x UPSLOT u partials
#define UPSLOT  (NOWN*NBLK*CH)                 // 524288 floats = 2MB

// ---- MALL-coherent uncached ops (writes + sync polling)
__device__ __forceinline__ void astore(float* p, float v) {
    __hip_atomic_store(p, v, __ATOMIC_RELAXED, __HIP_MEMORY_SCOPE_AGENT);
}
__device__ __forceinline__ void astoreu(unsigned* p, unsigned v) {
    __hip_atomic_store(p, v, __ATOMIC_RELAXED, __HIP_MEMORY_SCOPE_AGENT);
}
__device__ __forceinline__ unsigned aloadu(const unsigned* p) {
    return __hip_atomic_load(p, __ATOMIC_RELAXED, __HIP_MEMORY_SCOPE_AGENT);
}

// Sync A (all 256 produce partials; 64 owners consume): __syncthreads drains
// vmcnt so payload astores are at MALL before the flag stores issue. Distinct
// words per producer -> no RMW serialization.
__device__ __forceinline__ void sigA(unsigned* fl, int bid) {
    __syncthreads();
    if (threadIdx.x < NREPA) astoreu(&fl[threadIdx.x*256 + bid], 1u);
}
// Owners poll replica (bid&7): 8 owner-blocks x 64 lanes per replica — low
// fan-in (R1 lesson: high poller fan-in saturates the fabric).
__device__ __forceinline__ void pollA(const unsigned* fl, int bid) {
    if (threadIdx.x < 64) {
        const unsigned* p = fl + (bid & (NREPA-1))*256 + 4*threadIdx.x;
        for (;;) {
            unsigned a = aloadu(p) & aloadu(p+1) & aloadu(p+2) & aloadu(p+3);
            if (__all((int)a)) break;
            __builtin_amdgcn_s_sleep(2);
        }
    }
    __syncthreads();
}

// Sync B (64 owners produce reduced u; all 256 consume): owner bid writes ITS
// WORD in each of NREPB replicas (plain stores, distinct addresses). Consumer:
// 64 lanes poll the 64 owner words of replica (bid&15) -> 16 blocks/replica.
__device__ __forceinline__ void sigB(unsigned* fl, int bid) {
    __syncthreads();   // drain reduced-u / DP / B2R / UUP stores
    if (threadIdx.x < NREPB) astoreu(&fl[threadIdx.x*NOWN + bid], 1u);
}
__device__ __forceinline__ void pollB(const unsigned* fl, int bid) {
    if (threadIdx.x < 64) {
        const unsigned* p = fl + (bid & (NREPB-1))*NOWN + threadIdx.x;
        while (!__all(aloadu(p) != 0u))
            __builtin_amdgcn_s_sleep(2);
    }
    __syncthreads();
}

__device__ __forceinline__ float wave_sum64(float s) {
    #pragma unroll
    for (int m = 1; m < 64; m <<= 1) s += __shfl_xor(s, m, 64);
    return s;
}
// Reduce over lanes 0..31 (lane 0 result valid; halves stay independent).
__device__ __forceinline__ float sum32(float s) {
    #pragma unroll
    for (int m = 1; m < 32; m <<= 1) s += __shfl_xor(s, m, 64);
    return s;
}

// slab u contribution into LDS: row t=rg+64i, d = R[t][slab] . w_slab
__device__ __forceinline__ void u_pass_lds(const float4 (&rr)[RPT],
                                           const float* wsl, float* ubuf,
                                           int rg, int cg) {
    const float4 w4 = ((const float4*)wsl)[cg];
    #pragma unroll
    for (int i = 0; i < RPT; ++i) {
        float d = rr[i].x*w4.x + rr[i].y*w4.y + rr[i].z*w4.z + rr[i].w*w4.w;
        d += __shfl_xor(d, 1, 64);
        d += __shfl_xor(d, 2, 64);
        d += __shfl_xor(d, 4, 64);
        if (cg == 0) ubuf[rg + 64*i] = d;
    }
}

// Flush 2048 partials, 32-row-chunk layout UP[t>>5][bid][t&31]: SCALAR
// interleaved stores — per store-instruction the 64 lanes write 64
// consecutive t (two 128B dense runs). Per-instruction full-line packets
// (R9's float4 form: 8B/lane @16B stride = half-line packets, 2x WRITE_SIZE).
__device__ __forceinline__ void flush_up(float* UP, const float* ubuf,
                                         int bid, int tid) {
    #pragma unroll
    for (int r = 0; r < 4; ++r) {
        const int t = tid + 512*r;
        astore(&UP[(size_t)(t >> 5)*(NBLK*CH) + bid*CH + (t & 31)], ubuf[t]);
    }
}

// Owner (bid<64) reduces its 32-row chunk from 8KB of partials:
// 4 coalesced float4 loads/thread (fixed order m ascending), xor-shuffle
// {8,16,32} combines lanes sharing lane&7, LDS stage over waves. Returns
// this thread's reduced u (valid for tid<32), also stored to udst
// (uncached, 128B contiguous) and uhrow (LDS history).
__device__ __forceinline__ float owner_reduce(const float* __restrict__ UP,
                                              float* udst, float (*red)[8][4],
                                              float* uhrow, int bid,
                                              int tid, int lane, int wave) {
    const float4* b4 = (const float4*)(UP + (size_t)bid*(NBLK*CH));
    float4 s = b4[tid];
    #pragma unroll
    for (int m = 1; m < 4; ++m) {
        const float4 v = b4[tid + 512*m];
        s.x += v.x; s.y += v.y; s.z += v.z; s.w += v.w;
    }
    #pragma unroll
    for (int m = 8; m < 64; m <<= 1) {
        s.x += __shfl_xor(s.x, m, 64); s.y += __shfl_xor(s.y, m, 64);
        s.z += __shfl_xor(s.z, m, 64); s.w += __shfl_xor(s.w, m, 64);
    }
    if (lane < 8) {
        red[wave][lane][0] = s.x; red[wave][lane][1] = s.y;
        red[wave][lane][2] = s.z; red[wave][lane][3] = s.w;
    }
    __syncthreads();
    float u = 0.f;
    if (tid < 32) {
        #pragma unroll
        for (int w = 0; w < 8; ++w) u += red[w][tid >> 2][tid & 3];
        astore(&udst[bid*CH + tid], u);   // 32 lanes -> 128B contiguous
        uhrow[tid] = u;
    }
    return u;
}

// y slab partial: acc = -sum_t u[t]*R[t, my col4] over this thread's 32 rows
__device__ __forceinline__ float4 y_pass(const float4 (&rr)[RPT],
                                         const float* u, int rg) {
    float4 acc = make_float4(0.f, 0.f, 0.f, 0.f);
    #pragma unroll
    for (int i = 0; i < RPT; ++i) {
        const float ut = u[rg + 64*i];
        acc.x -= ut*rr[i].x; acc.y -= ut*rr[i].y;
        acc.z -= ut*rr[i].z; acc.w -= ut*rr[i].w;
    }
    return acc;
}

// Reduce per-thread y partials (over rg) into ysl[32]. Fixed order everywhere.
__device__ __forceinline__ void y_reduce(float4 acc, float (*red)[8][4],
                                         float* ysl, int wave, int lane, int tid) {
    #pragma unroll
    for (int m = 8; m < 64; m <<= 1) {
        acc.x += __shfl_xor(acc.x, m, 64); acc.y += __shfl_xor(acc.y, m, 64);
        acc.z += __shfl_xor(acc.z, m, 64); acc.w += __shfl_xor(acc.w, m, 64);
    }
    if (lane < 8) {
        red[wave][lane][0] = acc.x; red[wave][lane][1] = acc.y;
        red[wave][lane][2] = acc.z; red[wave][lane][3] = acc.w;
    }
    __syncthreads();
    if (tid < 32) {
        const int g = tid >> 2, comp = tid & 3;
        float s = 0.f;
        #pragma unroll
        for (int w = 0; w < 8; ++w) s += red[w][g][comp];
        ysl[g*4 + comp] = s;
    }
    __syncthreads();
}

__global__ __launch_bounds__(NTHR, 2) void k_all(
    const float* __restrict__ Rm, const float* __restrict__ f,
    const float* __restrict__ Dm, float* __restrict__ out,
    float* __restrict__ ws)
{
    __shared__ __align__(16) float ubuf[2048];
    __shared__ float red[8][8][4];
    __shared__ float uh[17][32];       // owner-only: chunk history for dots
    __shared__ __align__(16) float ysl[32];
    __shared__ __align__(16) float dirs[32];
    __shared__ __align__(16) float fsl[32];
    __shared__ float Wh[LORD][32];
    __shared__ float bh[LORD];
    __shared__ float alph[LORD];
    __shared__ float dotl[LORD];
    __shared__ float cf[LORD];
    __shared__ float misc[4];   // [0]=b2j  [2]=ff  [3]=uu

    unsigned* fupA  = (unsigned*)(ws + G_FUPA);
    unsigned* fredB = (unsigned*)(ws + G_FREDB);
    unsigned* fnum  = (unsigned*)(ws + G_FNUM);
    float* uraw = ws + G_URAW;
    float* UUP  = ws + G_UUP;
    float* FFP  = ws + G_FFP;
    float* B2P  = ws + G_B2P;
    float* B2R  = ws + G_B2R;
    float* DP   = ws + G_DP;
    float* NUMP = ws + G_NUMP;
    float* DENP = ws + G_DENP;
    float* UPB  = ws + G_UPB;

    const int tid = threadIdx.x, bid = blockIdx.x;
    const int cg = tid & 7, rg = tid >> 3;
    const int lane = tid & 63, wave = tid >> 6;
    const bool owner = bid < NOWN;

    // Load R column-slab into registers ONCE.
    const float4* R4 = (const float4*)Rm;
    float4 rr[RPT];
    #pragma unroll
    for (int i = 0; i < RPT; ++i)
        rr[i] = R4[(size_t)(rg + 64*i)*NC4 + (bid << 3) + cg];

    // ===== I1: f slab -> LDS ; FFP partial ; u_init partials (UP slot 16) =====
    if (wave == 0) {
        float4 fv = make_float4(0.f, 0.f, 0.f, 0.f);
        if (lane < 8) { fv = ((const float4*)f)[(bid << 3) + lane];
                        ((float4*)fsl)[lane] = fv; }
        float s2 = fv.x*fv.x + fv.y*fv.y + fv.z*fv.z + fv.w*fv.w;
        s2 += __shfl_xor(s2, 1, 64);
        s2 += __shfl_xor(s2, 2, 64);
        s2 += __shfl_xor(s2, 4, 64);
        if (lane == 0) astore(&FFP[bid], s2);
    }
    __syncthreads();
    u_pass_lds(rr, fsl, ubuf, rg, cg);
    __syncthreads();
    flush_up(UPB + (size_t)16*UPSLOT, ubuf, bid, tid);
    sigA(fupA + 16*NREPA*256, bid);

    // ===== I2 (owners): reduce UP16 -> uraw[16]=Rf ; uu partial =====
    if (owner) {
        pollA(fupA + 16*NREPA*256, bid);
        const float ureg = owner_reduce(UPB + (size_t)16*UPSLOT,
                                        uraw + 16*2048, red, uh[16],
                                        bid, tid, lane, wave);
        if (wave == 0) {
            float p = (lane < 32) ? ureg*ureg : 0.f;
            p = sum32(p);
            if (lane == 0) astore(&UUP[bid], p);
        }
        sigB(fredB + 16*NREPB*NOWN, bid);
    }
    pollB(fredB + 16*NREPB*NOWN, bid);

    // ===== I3: uu+ff reduce (all, fixed order) ; y=Hf ; W0 ; u(W0) slot 0 =====
    ((float4*)ubuf)[tid] = ((const float4*)(uraw + 16*2048))[tid];
    if (wave == 0) {
        float s = UUP[lane];          // 64 owner partials
        s = wave_sum64(s);
        if (lane == 0) misc[3] = s;
    }
    if (wave == 1) {
        float s = 0.f;
        #pragma unroll
        for (int i = 0; i < 4; ++i) s += FFP[lane + 64*i];
        s = wave_sum64(s);
        if (lane == 0) misc[2] = s;
    }
    __syncthreads();
    {
        float4 acc = y_pass(rr, ubuf, rg);
        y_reduce(acc, red, ysl, wave, lane, tid);
        const float E = -misc[3] / (misc[2] + 1e-15f);
        float v = 0.f;
        if (tid < 32) { v = E*fsl[tid] - ysl[tid]; Wh[0][tid] = v; }
        if (wave == 0) {
            float s = (lane < 32) ? v*v : 0.f;
            s = wave_sum64(s);
            if (lane == 0) astore(&B2P[0*256 + bid], s);
        }
        __syncthreads();
        u_pass_lds(rr, Wh[0], ubuf, rg, cg);
        __syncthreads();
        flush_up(UPB + (size_t)0*UPSLOT, ubuf, bid, tid);
    }
    sigA(fupA + 0*NREPA*256, bid);

    // ===== Lanczos steps j=0..15 =====
    for (int j = 0; j < LORD; ++j) {
        float* UPj = UPB + (size_t)j*UPSLOT;
        float* DPj = DP + j*(16*NOWN);
        // --- Phase 1 (owners): reduce u ; wave0 dots vs history ; wave1 b2 ---
        if (owner) {
            pollA(fupA + j*NREPA*256, bid);
            const float ureg = owner_reduce(UPj, uraw + (size_t)j*2048, red,
                                            uh[j], bid, tid, lane, wave);
            if (wave == 0) {
                #pragma unroll 1
                for (int k = 0; k <= j; ++k) {
                    float p = (lane < 32) ? ureg * uh[k][lane] : 0.f;
                    p = sum32(p);
                    if (lane == 0) astore(&DPj[k*NOWN + bid], p);
                }
            }
            if (wave == 1) {   // b2 pre-reduce: B2P visible after pollA
                float s = 0.f;
                #pragma unroll
                for (int i = 0; i < 4; ++i) s += B2P[j*256 + lane + 64*i];
                s = wave_sum64(s);
                if (lane == 0) astore(&B2R[j*64 + bid], s);
            }
            sigB(fredB + j*NREPB*NOWN, bid);
        }
        pollB(fredB + j*NREPB*NOWN, bid);

        // --- Phase 2 (all): RAW u -> ubuf (float4, early); dots reduce;
        // b2 from owner pre-reduce (1 word); one barrier covers all. ---
        if (j < LORD - 1)
            ((float4*)ubuf)[tid] = ((const float4*)(uraw + (size_t)j*2048))[tid];
        for (int k = wave; k <= j; k += 8) {
            float s = DPj[k*NOWN + lane];     // 64 owner partials
            s = wave_sum64(s);
            if (lane == 0) dotl[k] = s;
        }
        if (tid == 256) misc[0] = B2R[j*64 + (bid & 63)];
        __syncthreads();
        const float b2j = misc[0];
        const float bj  = sqrtf(fmaxf(b2j, 1e-60f));   // ref: w/max(b,1e-30)
        if (tid == 0) {
            bh[j]   = bj;
            alph[j] = -dotl[j] / fmaxf(b2j, 1e-60f);
        }
        if (j < LORD - 1) {
            float4 acc = y_pass(rr, ubuf, rg);   // RAW u
            y_reduce(acc, red, ysl, wave, lane, tid);
            const float inv = 1.0f / bj;
            // W_{j+1} = y/bj + sum_{k<=j} dot_jk/(b_j b_k^2) W_k (full reorth)
            float v = 0.f;
            if (tid < 32) {
                v = ysl[tid] * inv;
                for (int k = 0; k <= j; ++k)
                    v += (dotl[k] / (bj * bh[k] * bh[k])) * Wh[k][tid];
                Wh[j+1][tid] = v;
            }
            if (wave == 0) {
                float s = (lane < 32) ? v*v : 0.f;
                s = wave_sum64(s);
                if (lane == 0) astore(&B2P[(j+1)*256 + bid], s);
            }
            __syncthreads();
            u_pass_lds(rr, Wh[j+1], ubuf, rg, cg);
            __syncthreads();
            flush_up(UPB + (size_t)(j+1)*UPSLOT, ubuf, bid, tid);
            sigA(fupA + (j+1)*NREPA*256, bid);
        } else {
            __syncthreads();   // alph[15]/bh[15] visible
            // coeffs = normF * exp(-tau*T) e0 via fp64 Taylor — computed
            // REDUNDANTLY by every block (alph/bh are block-local and
            // bit-identical): no MALL hop.
            if (wave == 0) {
                double a = 0.0, bl = 0.0;
                if (lane < LORD)     a  = (double)alph[lane];
                if (lane < LORD - 1) bl = (double)bh[lane + 1];
                double bprev = __shfl_up(bl, 1, 64);
                if (lane == 0) bprev = 0.0;
                if (lane >= LORD) { a = 0.0; bl = 0.0; bprev = 0.0; }
                double v = (lane == 0) ? 1.0 : 0.0;
                double accd = v;
                for (int n = 1; n <= 30; ++n) {
                    double vm = __shfl_up(v, 1, 64);
                    if (lane == 0) vm = 0.0;
                    double vp = __shfl_down(v, 1, 64);
                    if (lane >= LORD - 1) vp = 0.0;
                    const double tv = a*v + bprev*vm + bl*vp;
                    v = tv * (-0.08 / (double)n);
                    accd += v;
                }
                if (lane < LORD)
                    cf[lane] = (float)accd * bh[0];
            }
            __syncthreads();   // cf visible to all waves
        }
    }

    // ===== F1: dir slab from LDS W history ; num/den partials =====
    if (tid < 32) {
        float s = 0.f;
        #pragma unroll
        for (int l = 0; l < LORD; ++l) s += cf[l] * Wh[l][tid] / bh[l];
        dirs[tid] = s;
    }
    __syncthreads();
    if (wave == 0 && lane < 16) {
        const float4* Dp = (const float4*)Dm + (size_t)lane*NC4 + (bid << 3);
        float num = 0.f, den = 0.f;
        #pragma unroll
        for (int g = 0; g < 8; ++g) {
            const float4 dv = Dp[g];
            const float4 dr = ((const float4*)dirs)[g];
            num += dv.x*dr.x + dv.y*dr.y + dv.z*dr.z + dv.w*dr.w;
            den += dv.x*dv.x + dv.y*dv.y + dv.z*dv.z + dv.w*dv.w;
        }
        astore(&NUMP[lane*256 + bid], num);
        astore(&DENP[lane*256 + bid], den);
    }
    sigA(fnum, bid);
    // Blocks != 0 are done; only block 0 waits for all num/den partials.

    // ===== F2: block 0 reduces num/den deterministically, writes out =====
    if (bid == 0) {
        pollA(fnum, 0);
        for (int p = wave; p < 16; p += 8) {
            float n = 0.f, d = 0.f;
            #pragma unroll
            for (int i = 0; i < 4; ++i) {
                n += NUMP[p*256 + lane + 64*i];
                d += DENP[p*256 + lane + 64*i];
            }
            n = wave_sum64(n);
            d = wave_sum64(d);
            if (lane == 0) out[p] = n / (d + 1e-4f);
        }
    }
}

extern "C" void kernel_launch(void* const* d_in, const int* in_sizes, int n_in,
                              void* d_out, int out_size, void* d_ws, size_t ws_size,
                              hipStream_t stream)
{
    (void)in_sizes; (void)n_in; (void)out_size; (void)ws_size;
    const float* f  = (const float*)d_in[0];
    const float* Rm = (const float*)d_in[1];
    const float* Dm = (const float*)d_in[2];
    float* outp = (float*)d_out;
    float* ws   = (float*)d_ws;
    // Zero flags (~212 KB). All rotated payload buffers are written before
    // their single read each launch.
    hipMemsetAsync(ws, 0, G_ZEND * sizeof(float), stream);
    // REGULAR launch (R7-validated: cut harness-visible overhead ~50us):
    // grid 256 blocks <= resident capacity, co-residency structurally
    // guaranteed; all inter-block sync is hand-rolled flag-based.
    hipLaunchKernelGGL(k_all, dim3(NBLK), dim3(NTHR), 0, stream,
                       Rm, f, Dm, outp, ws);
}

// Round 11
// 283.313 us; speedup vs baseline: 1.0910x; 1.0685x over previous
//
#include <hip/hip_runtime.h>
#include <math.h>

// Problem constants
#define D_FEAT 8192
#define NC4    2048          // float4 columns per R row
#define T_RES  2048
#define LORD   16

// Geometry: 256 blocks x 512 threads (1 block/CU). Block owns a 32-column slab
// of R (all 2048 rows) in registers: thread (cg=tid&7, rg=tid>>3) holds rows
// rg+64*i (i<32) of float4-column (bid*8+cg). 32 float4 = 128 regs.
// R11 = EXACT R8 revert (best measured kernel: 207.5us, JSON 284).
// R9/R10's micro-opt bundle (wave0-SERIAL dots, single-thread B2R read,
// vectorized owner reduce) was net -16us: the serial dependent sum32 chain
// (136 reductions across steps) sat on the critical path before sigB where
// R8 spreads dots over 8 waves in parallel. Measured ranking:
// R8 207.5 < R3 215.7 < R10 223.5 < R7 232 (packet rule confirmed 5x:
// per-INSTRUCTION lane-contiguous full 64B lines; half-line = +25-28us).
#define NTHR 512
#define NBLK 256
#define RPT  32
#define NOWN 64              // u-reduction chunk owners (32 rows each)
#define CH   32              // rows per chunk
#define NREPA 8              // A-flag replicas (pollers = 64 owners -> 8/rep)
#define NREPB 16             // B-flag replicas (pollers = 256 blocks -> 16/rep)

// ---- Global workspace layout (float offsets) ----
// Zeroed region: flags (~220 KB memset per launch).
#define G_FUPA  0                              // 17 x NREPA x 256 partial-ready
#define G_FREDB (G_FUPA + 17*NREPA*256)        // 17 x NREPB x NOWN owner words
#define G_FNUM  (G_FREDB + 17*NREPB*NOWN)      // NREPA x 256 (block 0 polls)
#define G_ZEND  (G_FNUM + NREPA*256)
// Rotated single-write-then-single-read regions (cached reads safe: caches
// invalidated at dispatch; each slot written once then read once per launch):
#define G_URAW  G_ZEND                         // 17 x 2048 reduced u (slot16 = R f)
#define G_UUP   (G_URAW + 17*2048)             // 64 |u_init|^2 owner partials
#define G_FFP   (G_UUP + 64)                   // 256 f.f partials
#define G_B2P   (G_FFP + 256)                  // 16 x 256 b2 partials (slot j)
#define G_DP    (G_B2P + 16*256)               // 16 x 16 x 64 dot owner partials
#define G_NUMP  (G_DP + 16*16*64)              // 16 x 256
#define G_DENP  (G_NUMP + 16*256)              // 16 x 256
#define G_UPB   ((G_DENP + 16*256 + 1023) & ~1023)  // 17 x UPSLOT u partials
#define UPSLOT  (NOWN*NBLK*CH)                 // 524288 floats = 2MB

// ---- MALL-coherent uncached ops (writes + sync polling)
__device__ __forceinline__ void astore(float* p, float v) {
    __hip_atomic_store(p, v, __ATOMIC_RELAXED, __HIP_MEMORY_SCOPE_AGENT);
}
__device__ __forceinline__ void astoreu(unsigned* p, unsigned v) {
    __hip_atomic_store(p, v, __ATOMIC_RELAXED, __HIP_MEMORY_SCOPE_AGENT);
}
__device__ __forceinline__ unsigned aloadu(const unsigned* p) {
    return __hip_atomic_load(p, __ATOMIC_RELAXED, __HIP_MEMORY_SCOPE_AGENT);
}

// Sync A (all 256 produce partials; 64 owners consume): __syncthreads drains
// vmcnt so payload astores are at MALL before the flag stores issue. Distinct
// words per producer -> no RMW serialization.
__device__ __forceinline__ void sigA(unsigned* fl, int bid) {
    __syncthreads();
    if (threadIdx.x < NREPA) astoreu(&fl[threadIdx.x*256 + bid], 1u);
}
// Owners poll replica (bid&7): 8 owner-blocks x 64 lanes per replica — low
// fan-in (R1 lesson: high poller fan-in saturates the fabric).
__device__ __forceinline__ void pollA(const unsigned* fl, int bid) {
    if (threadIdx.x < 64) {
        const unsigned* p = fl + (bid & (NREPA-1))*256 + 4*threadIdx.x;
        for (;;) {
            unsigned a = aloadu(p) & aloadu(p+1) & aloadu(p+2) & aloadu(p+3);
            if (__all((int)a)) break;
            __builtin_amdgcn_s_sleep(2);
        }
    }
    __syncthreads();
}

// Sync B (64 owners produce reduced u; all 256 consume): owner bid writes ITS
// WORD in each of NREPB replicas (plain stores, distinct addresses). Consumer:
// 64 lanes poll the 64 owner words of replica (bid&15) -> 16 blocks/replica.
__device__ __forceinline__ void sigB(unsigned* fl, int bid) {
    __syncthreads();   // drain reduced-u / DP / UUP stores
    if (threadIdx.x < NREPB) astoreu(&fl[threadIdx.x*NOWN + bid], 1u);
}
__device__ __forceinline__ void pollB(const unsigned* fl, int bid) {
    if (threadIdx.x < 64) {
        const unsigned* p = fl + (bid & (NREPB-1))*NOWN + threadIdx.x;
        while (!__all(aloadu(p) != 0u))
            __builtin_amdgcn_s_sleep(2);
    }
    __syncthreads();
}

__device__ __forceinline__ float wave_sum64(float s) {
    #pragma unroll
    for (int m = 1; m < 64; m <<= 1) s += __shfl_xor(s, m, 64);
    return s;
}
// Reduce over lanes 0..31 (values on lanes >=32 must be 0/unused).
__device__ __forceinline__ float sum32(float s) {
    #pragma unroll
    for (int m = 1; m < 32; m <<= 1) s += __shfl_xor(s, m, 64);
    return s;
}

// slab u contribution into LDS: row t=rg+64i, d = R[t][slab] . w_slab
__device__ __forceinline__ void u_pass_lds(const float4 (&rr)[RPT],
                                           const float* wsl, float* ubuf,
                                           int rg, int cg) {
    const float4 w4 = ((const float4*)wsl)[cg];
    #pragma unroll
    for (int i = 0; i < RPT; ++i) {
        float d = rr[i].x*w4.x + rr[i].y*w4.y + rr[i].z*w4.z + rr[i].w*w4.w;
        d += __shfl_xor(d, 1, 64);
        d += __shfl_xor(d, 2, 64);
        d += __shfl_xor(d, 4, 64);
        if (cg == 0) ubuf[rg + 64*i] = d;
    }
}

// Flush 2048 partials, 32-row-chunk layout UP[t>>5][bid][t&31]: per wave-instr
// each 32-lane half writes one contiguous 128B run -> full-line write packets
// (R7/R9 lesson: half-line packets cost ~25-28us; coalescing is
// per-INSTRUCTION lane-contiguity, not per-thread contiguity).
__device__ __forceinline__ void flush_up(float* UP, const float* ubuf,
                                         int bid, int tid) {
    #pragma unroll
    for (int r = 0; r < 4; ++r) {
        const int t = tid + 512*r;
        astore(&UP[(size_t)(t >> 5)*(NBLK*CH) + bid*CH + (t & 31)], ubuf[t]);
    }
}

// Owner (bid<64) reduces its 32-row chunk: one contiguous 32KB streaming
// CACHED read (slot written-once this launch). Fixed order everywhere.
__device__ __forceinline__ void reduce_up32(const float* __restrict__ UP,
                                            float* udst, float (*red2)[17],
                                            float* ufin32, float* uhrow,
                                            int bid, int tid) {
    const int r = tid & 31, q = tid >> 5;   // 16 groups x 16 partials
    const float* base = UP + (size_t)bid*(NBLK*CH);
    float s = 0.f;
    #pragma unroll
    for (int i = 0; i < 16; ++i) s += base[(q*16 + i)*CH + r];
    red2[r][q] = s;
    __syncthreads();
    if (tid < 32) {
        float u = 0.f;
        #pragma unroll
        for (int q2 = 0; q2 < 16; ++q2) u += red2[tid][q2];
        ufin32[tid] = u;
        uhrow[tid] = u;
        astore(&udst[bid*CH + tid], u);   // 32 lanes -> 128B contiguous
    }
    __syncthreads();
}

// y slab partial: acc = -sum_t u[t]*R[t, my col4] over this thread's 32 rows
__device__ __forceinline__ float4 y_pass(const float4 (&rr)[RPT],
                                         const float* u, int rg) {
    float4 acc = make_float4(0.f, 0.f, 0.f, 0.f);
    #pragma unroll
    for (int i = 0; i < RPT; ++i) {
        const float ut = u[rg + 64*i];
        acc.x -= ut*rr[i].x; acc.y -= ut*rr[i].y;
        acc.z -= ut*rr[i].z; acc.w -= ut*rr[i].w;
    }
    return acc;
}

// Reduce per-thread y partials (over rg) into ysl[32]. Fixed order everywhere.
__device__ __forceinline__ void y_reduce(float4 acc, float (*red)[8][4],
                                         float* ysl, int wave, int lane, int tid) {
    #pragma unroll
    for (int m = 8; m < 64; m <<= 1) {
        acc.x += __shfl_xor(acc.x, m, 64); acc.y += __shfl_xor(acc.y, m, 64);
        acc.z += __shfl_xor(acc.z, m, 64); acc.w += __shfl_xor(acc.w, m, 64);
    }
    if (lane < 8) {
        red[wave][lane][0] = acc.x; red[wave][lane][1] = acc.y;
        red[wave][lane][2] = acc.z; red[wave][lane][3] = acc.w;
    }
    __syncthreads();
    if (tid < 32) {
        const int g = tid >> 2, comp = tid & 3;
        float s = 0.f;
        #pragma unroll
        for (int w = 0; w < 8; ++w) s += red[w][g][comp];
        ysl[g*4 + comp] = s;
    }
    __syncthreads();
}

__global__ __launch_bounds__(NTHR, 2) void k_all(
    const float* __restrict__ Rm, const float* __restrict__ f,
    const float* __restrict__ Dm, float* __restrict__ out,
    float* __restrict__ ws)
{
    __shared__ __align__(16) float ubuf[2048];
    __shared__ float red2[32][17];
    __shared__ float red[8][8][4];
    __shared__ float ufin32[32];
    __shared__ float uh[17][32];       // owner-only: chunk history for dots
    __shared__ __align__(16) float ysl[32];
    __shared__ __align__(16) float dirs[32];
    __shared__ __align__(16) float fsl[32];
    __shared__ float Wh[LORD][32];
    __shared__ float bh[LORD];
    __shared__ float alph[LORD];
    __shared__ float dotl[LORD];
    __shared__ float cf[LORD];
    __shared__ float misc[4];   // [0]=b2j  [2]=ff  [3]=uu

    unsigned* fupA  = (unsigned*)(ws + G_FUPA);
    unsigned* fredB = (unsigned*)(ws + G_FREDB);
    unsigned* fnum  = (unsigned*)(ws + G_FNUM);
    float* uraw = ws + G_URAW;
    float* UUP  = ws + G_UUP;
    float* FFP  = ws + G_FFP;
    float* B2P  = ws + G_B2P;
    float* DP   = ws + G_DP;
    float* NUMP = ws + G_NUMP;
    float* DENP = ws + G_DENP;
    float* UPB  = ws + G_UPB;

    const int tid = threadIdx.x, bid = blockIdx.x;
    const int cg = tid & 7, rg = tid >> 3;
    const int lane = tid & 63, wave = tid >> 6;
    const bool owner = bid < NOWN;

    // Load R column-slab into registers ONCE.
    const float4* R4 = (const float4*)Rm;
    float4 rr[RPT];
    #pragma unroll
    for (int i = 0; i < RPT; ++i)
        rr[i] = R4[(size_t)(rg + 64*i)*NC4 + (bid << 3) + cg];

    // ===== I1: f slab -> LDS ; FFP partial ; u_init partials (UP slot 16) =====
    if (wave == 0) {
        float4 fv = make_float4(0.f, 0.f, 0.f, 0.f);
        if (lane < 8) { fv = ((const float4*)f)[(bid << 3) + lane];
                        ((float4*)fsl)[lane] = fv; }
        float s2 = fv.x*fv.x + fv.y*fv.y + fv.z*fv.z + fv.w*fv.w;
        s2 += __shfl_xor(s2, 1, 64);
        s2 += __shfl_xor(s2, 2, 64);
        s2 += __shfl_xor(s2, 4, 64);
        if (lane == 0) astore(&FFP[bid], s2);
    }
    __syncthreads();
    u_pass_lds(rr, fsl, ubuf, rg, cg);
    __syncthreads();
    flush_up(UPB + (size_t)16*UPSLOT, ubuf, bid, tid);
    sigA(fupA + 16*NREPA*256, bid);

    // ===== I2 (owners): reduce UP16 -> uraw[16]=Rf ; uu partial =====
    if (owner) {
        pollA(fupA + 16*NREPA*256, bid);
        reduce_up32(UPB + (size_t)16*UPSLOT, uraw + 16*2048, red2, ufin32,
                    uh[16], bid, tid);
        if (wave == 0) {
            float p = (lane < 32) ? ufin32[lane]*ufin32[lane] : 0.f;
            p = sum32(p);
            if (lane == 0) astore(&UUP[bid], p);
        }
        sigB(fredB + 16*NREPB*NOWN, bid);
    }
    pollB(fredB + 16*NREPB*NOWN, bid);

    // ===== I3: uu+ff reduce (all, fixed order) ; y=Hf ; W0 ; u(W0) slot 0 =====
    #pragma unroll
    for (int r = 0; r < 4; ++r)
        ubuf[tid + 512*r] = uraw[16*2048 + tid + 512*r];
    if (wave == 0) {
        float s = UUP[lane];          // 64 owner partials
        s = wave_sum64(s);
        if (lane == 0) misc[3] = s;
    }
    if (wave == 1) {
        float s = 0.f;
        #pragma unroll
        for (int i = 0; i < 4; ++i) s += FFP[lane + 64*i];
        s = wave_sum64(s);
        if (lane == 0) misc[2] = s;
    }
    __syncthreads();
    {
        float4 acc = y_pass(rr, ubuf, rg);
        y_reduce(acc, red, ysl, wave, lane, tid);
        const float E = -misc[3] / (misc[2] + 1e-15f);
        float v = 0.f;
        if (tid < 32) { v = E*fsl[tid] - ysl[tid]; Wh[0][tid] = v; }
        if (wave == 0) {
            float s = (lane < 32) ? v*v : 0.f;
            s = wave_sum64(s);
            if (lane == 0) astore(&B2P[0*256 + bid], s);
        }
        __syncthreads();
        u_pass_lds(rr, Wh[0], ubuf, rg, cg);
        __syncthreads();
        flush_up(UPB + (size_t)0*UPSLOT, ubuf, bid, tid);
    }
    sigA(fupA + 0*NREPA*256, bid);

    // ===== Lanczos steps j=0..15 =====
    for (int j = 0; j < LORD; ++j) {
        float* UPj = UPB + (size_t)j*UPSLOT;
        float* DPj = DP + j*(16*NOWN);
        // --- Phase 1 (owners): reduce u ; dot partials vs chunk history ---
        if (owner) {
            pollA(fupA + j*NREPA*256, bid);
            reduce_up32(UPj, uraw + (size_t)j*2048, red2, ufin32, uh[j],
                        bid, tid);
            for (int k = wave; k <= j; k += 8) {
                float p = (lane < 32) ? ufin32[lane]*uh[k][lane] : 0.f;
                p = sum32(p);
                if (lane == 0) astore(&DPj[k*NOWN + bid], p);
            }
            sigB(fredB + j*NREPB*NOWN, bid);
        }
        pollB(fredB + j*NREPB*NOWN, bid);

        // --- Phase 2 (all): RAW u -> ubuf immediately (loads overlap the dot
        // and b2 reduces); one barrier covers ubuf+dotl+misc; 1/bj folded
        // into the 32-value W update (y is linear in u). ---
        if (j < LORD - 1) {
            #pragma unroll
            for (int r = 0; r < 4; ++r)
                ubuf[tid + 512*r] = uraw[(size_t)j*2048 + tid + 512*r];
        }
        for (int k = wave; k <= j; k += 8) {
            float s = DPj[k*NOWN + lane];     // 64 owner partials
            s = wave_sum64(s);
            if (lane == 0) dotl[k] = s;
        }
        if (wave == 1) {   // every block reduces B2P[j] identically
            float s = 0.f;
            #pragma unroll
            for (int i = 0; i < 4; ++i) s += B2P[j*256 + lane + 64*i];
            s = wave_sum64(s);
            if (lane == 0) misc[0] = s;
        }
        __syncthreads();
        const float b2j = misc[0];
        const float bj  = sqrtf(fmaxf(b2j, 1e-60f));   // ref: w/max(b,1e-30)
        if (tid == 0) {
            bh[j]   = bj;
            alph[j] = -dotl[j] / fmaxf(b2j, 1e-60f);
        }
        if (j < LORD - 1) {
            float4 acc = y_pass(rr, ubuf, rg);   // RAW u
            y_reduce(acc, red, ysl, wave, lane, tid);
            const float inv = 1.0f / bj;
            // W_{j+1} = y/bj + sum_{k<=j} dot_jk/(b_j b_k^2) W_k (full reorth)
            float v = 0.f;
            if (tid < 32) {
                v = ysl[tid] * inv;
                for (int k = 0; k <= j; ++k)
                    v += (dotl[k] / (bj * bh[k] * bh[k])) * Wh[k][tid];
                Wh[j+1][tid] = v;
            }
            if (wave == 0) {
                float s = (lane < 32) ? v*v : 0.f;
                s = wave_sum64(s);
                if (lane == 0) astore(&B2P[(j+1)*256 + bid], s);
            }
            __syncthreads();
            u_pass_lds(rr, Wh[j+1], ubuf, rg, cg);
            __syncthreads();
            flush_up(UPB + (size_t)(j+1)*UPSLOT, ubuf, bid, tid);
            sigA(fupA + (j+1)*NREPA*256, bid);
        } else {
            __syncthreads();   // alph[15]/bh[15] visible
            // coeffs = normF * exp(-tau*T) e0 via fp64 Taylor — computed
            // REDUNDANTLY by every block (alph/bh are block-local and
            // bit-identical): no MALL hop.
            if (wave == 0) {
                double a = 0.0, bl = 0.0;
                if (lane < LORD)     a  = (double)alph[lane];
                if (lane < LORD - 1) bl = (double)bh[lane + 1];
                double bprev = __shfl_up(bl, 1, 64);
                if (lane == 0) bprev = 0.0;
                if (lane >= LORD) { a = 0.0; bl = 0.0; bprev = 0.0; }
                double v = (lane == 0) ? 1.0 : 0.0;
                double accd = v;
                for (int n = 1; n <= 30; ++n) {
                    double vm = __shfl_up(v, 1, 64);
                    if (lane == 0) vm = 0.0;
                    double vp = __shfl_down(v, 1, 64);
                    if (lane >= LORD - 1) vp = 0.0;
                    const double tv = a*v + bprev*vm + bl*vp;
                    v = tv * (-0.08 / (double)n);
                    accd += v;
                }
                if (lane < LORD)
                    cf[lane] = (float)accd * bh[0];
            }
            __syncthreads();   // cf visible to all waves
        }
    }

    // ===== F1: dir slab from LDS W history ; num/den partials =====
    if (tid < 32) {
        float s = 0.f;
        #pragma unroll
        for (int l = 0; l < LORD; ++l) s += cf[l] * Wh[l][tid] / bh[l];
        dirs[tid] = s;
    }
    __syncthreads();
    if (wave == 0 && lane < 16) {
        const float4* Dp = (const float4*)Dm + (size_t)lane*NC4 + (bid << 3);
        float num = 0.f, den = 0.f;
        #pragma unroll
        for (int g = 0; g < 8; ++g) {
            const float4 dv = Dp[g];
            const float4 dr = ((const float4*)dirs)[g];
            num += dv.x*dr.x + dv.y*dr.y + dv.z*dr.z + dv.w*dr.w;
            den += dv.x*dv.x + dv.y*dv.y + dv.z*dv.z + dv.w*dv.w;
        }
        astore(&NUMP[lane*256 + bid], num);
        astore(&DENP[lane*256 + bid], den);
    }
    sigA(fnum, bid);
    // Blocks != 0 are done; only block 0 waits for all num/den partials.

    // ===== F2: block 0 reduces num/den deterministically, writes out =====
    if (bid == 0) {
        pollA(fnum, 0);
        for (int p = wave; p < 16; p += 8) {
            float n = 0.f, d = 0.f;
            #pragma unroll
            for (int i = 0; i < 4; ++i) {
                n += NUMP[p*256 + lane + 64*i];
                d += DENP[p*256 + lane + 64*i];
            }
            n = wave_sum64(n);
            d = wave_sum64(d);
            if (lane == 0) out[p] = n / (d + 1e-4f);
        }
    }
}

extern "C" void kernel_launch(void* const* d_in, const int* in_sizes, int n_in,
                              void* d_out, int out_size, void* d_ws, size_t ws_size,
                              hipStream_t stream)
{
    (void)in_sizes; (void)n_in; (void)out_size; (void)ws_size;
    const float* f  = (const float*)d_in[0];
    const float* Rm = (const float*)d_in[1];
    const float* Dm = (const float*)d_in[2];
    float* outp = (float*)d_out;
    float* ws   = (float*)d_ws;
    // Zero flags (~220 KB). All rotated payload buffers are written before
    // their single read each launch.
    hipMemsetAsync(ws, 0, G_ZEND * sizeof(float), stream);
    // REGULAR launch (R7-validated: cut harness-visible overhead ~50us):
    // grid 256 blocks <= resident capacity, co-residency structurally
    // guaranteed; all inter-block sync is hand-rolled flag-based.
    hipLaunchKernelGGL(k_all, dim3(NBLK), dim3(NTHR), 0, stream,
                       Rm, f, Dm, outp, ws);
}